// Round 14
// baseline (190.820 us; speedup 1.0000x reference)
//
#include <hip/hip_runtime.h>
#include <math.h>

typedef __attribute__((ext_vector_type(4))) float floatx4;
typedef __attribute__((ext_vector_type(8))) short shortx8;   // 8 bf16
typedef __attribute__((ext_vector_type(4))) short shortx4;   // 4 bf16 (8B)

#define NB 4
#define CC 768
#define WW 2048
#define HH 12
#define DD 64
#define GG 4
#define CG 192
#define HPG 3
#define L2E 1.4426950408889634f
#define C18 0.18033688011112043f   // 0.125 * log2(e)
#define MSH 11.541560327111707f    // 8.0 * log2(e)  (fixed softmax shift)

__device__ __forceinline__ float fast_exp2(float x) {
    return __builtin_amdgcn_exp2f(x);   // v_exp_f32 (log2 domain)
}

__device__ __forceinline__ short f2bf(float f) {
    union { float f; unsigned u; } v; v.f = f;
    unsigned r = v.u + 0x7fffu + ((v.u >> 16) & 1u);   // RNE
    return (short)(r >> 16);
}

// v_cvt_pk_bf16_f32: lo16 <- src0, hi16 <- src1 (RNE)  [learn_hip m214v22]
__device__ __forceinline__ int cvtpk(float lo, float hi) {
    int r;
    asm("v_cvt_pk_bf16_f32 %0, %1, %2" : "=v"(r) : "v"(lo), "v"(hi));
    return r;
}

__device__ __forceinline__ shortx8 mk8(int a, int b, int c, int d) {
    union { int i[4]; shortx8 h; } u;
    u.i[0] = a; u.i[1] = b; u.i[2] = c; u.i[3] = d;
    return u.h;
}

// K-buffer swizzle (R12-verified: conflicts 6.68M -> 0.39M). K-read 8-lane
// service groups cover rows {B..B+3, B+8..B+11}; fK(r) = (r1 r0, r3<<2) is
// bank-distinct on every group. Semantics swizzle-independent (pre-swizzled
// global source; read XORs the same fK(r) back out).
__device__ __forceinline__ int swzK(int r) {
    return (r & 3) | (((r >> 3) & 1) << 2);
}
// V-buffer swizzle: V read groups cover 8 CONSECUTIVE rows c..c+7 ->
// identity low-3-bits is bijective per service group (R4-verified).
__device__ __forceinline__ int swzV(int r) {
    return r & 7;
}

// async global->LDS, 16B per lane; lds base must be wave-uniform
__device__ __forceinline__ void gl_lds16(const void* g, void* l) {
    __builtin_amdgcn_global_load_lds(
        (const __attribute__((address_space(1))) unsigned int*)g,
        (__attribute__((address_space(3))) unsigned int*)l, 16, 0, 0);
}

// ---------------------------------------------------------------------------
// qkv_gemm v4: ONE block per tile computes ALL THREE mats, and builds weight
// A-fragments DIRECTLY from f32 w (no prep_w kernel, no Wf intermediate).
// Fragment algebra (verified vs prep_w's off formula):
//   ah[mi][j] = f2bf( w[g][(wid*3+mi)*16 + l15][ks*32 + quad*8 + j] )
// w[g] = 147KB, L2-resident, shared by the 128 blocks of that group.
// x tile staged+transposed ONCE. [0,24576): Xh_l  [24576,50688): scratch
// (Th 9216 B staging, then T per-mat epilogue). grid: 512 blocks, 256 thr.
// ---------------------------------------------------------------------------
__global__ __launch_bounds__(256) void qkv_gemm(
    const float* __restrict__ x,
    const float* __restrict__ wq, const float* __restrict__ wk,
    const float* __restrict__ wv,
    const float* __restrict__ bq, const float* __restrict__ bk,
    const float* __restrict__ bv,
    short* __restrict__ Qb, short* __restrict__ Kb, short* __restrict__ Vb)
{
    __shared__ __align__(16) char smem[50688];
    short* Xh_l = (short*)smem;              // 24576 B, [p][24 chunks] swz
    short* Th   = (short*)(smem + 24576);    // staging transpose scratch

    const int tile = blockIdx.x;            // 0..511
    const int p0   = (tile & 31) * 64;
    const int g    = (tile >> 5) & 3;
    const int n    = tile >> 7;

    const int tid  = threadIdx.x;
    const int wid  = __builtin_amdgcn_readfirstlane(tid >> 6);
    const int lane = tid & 63;
    const int l15  = lane & 15;
    const int quad = lane >> 4;
    const int ob   = wid * 48;

    // ---- fused transpose staging (ONCE): x [c][w] f32 -> Xh_l swizzled ----
    {
        const int w  = tid & 63;
        const int cb = (tid >> 6) * 16;
        const int wr = tid >> 2;
        const int cc = (tid & 3) * 16;       // shorts within slab
        for (int s = 0; s < 3; ++s) {
            const float* xb = x + ((size_t)n * CC + g * CG + s * 64 + cb) * WW + p0 + w;
            float xv[16];
            #pragma unroll
            for (int j = 0; j < 16; ++j) xv[j] = xb[(size_t)j * WW];
            shortx8 h0, h1;
            #pragma unroll
            for (int j = 0; j < 8; ++j) { h0[j] = f2bf(xv[j]); h1[j] = f2bf(xv[j + 8]); }
            *(shortx8*)&Th[w * 72 + cb]     = h0;
            *(shortx8*)&Th[w * 72 + cb + 8] = h1;
            __syncthreads();
            shortx8 v0 = *(const shortx8*)&Th[wr * 72 + cc];
            shortx8 v1 = *(const shortx8*)&Th[wr * 72 + cc + 8];
            const int ch0 = s * 8 + (cc >> 3);           // even chunk
            const int ch1 = ch0 + 1;
            const int sc0 = (ch0 & ~7) | ((ch0 & 7) ^ (wr & 7));
            const int sc1 = (ch1 & ~7) | ((ch1 & 7) ^ (wr & 7));
            *(shortx8*)&Xh_l[(wr * 24 + sc0) * 8] = v0;
            *(shortx8*)&Xh_l[(wr * 24 + sc1) * 8] = v1;
            __syncthreads();                 // Th reuse / final: frags ready
        }
    }

    // per-lane weight row base (row = (wid*3+mi)*16 + l15 within group g)
    const size_t wrow0 = (size_t)(g * CG + wid * 48 + l15) * CG;

    #pragma unroll 1
    for (int mat = 0; mat < 3; ++mat) {
        const float* wsrc = (mat == 0) ? wq : (mat == 1) ? wk : wv;
        const float* bias = (mat == 0) ? bq : (mat == 1) ? bk : bv;
        short* Y = (mat == 0) ? Qb : (mat == 1) ? Kb : Vb;

        floatx4 acc[3][4];
        #pragma unroll
        for (int mi = 0; mi < 3; ++mi)
            #pragma unroll
            for (int ni = 0; ni < 4; ++ni) acc[mi][ni] = (floatx4)0.0f;

        #pragma unroll
        for (int ks = 0; ks < 6; ++ks) {
            shortx8 ah[3], bh[4];
            #pragma unroll
            for (int mi = 0; mi < 3; ++mi) {
                const float* wp = wsrc + wrow0 + (size_t)mi * 16 * CG + ks * 32 + quad * 8;
                float4 wa = *(const float4*)wp;
                float4 wb = *(const float4*)(wp + 4);
                shortx8 a;
                a[0] = f2bf(wa.x); a[1] = f2bf(wa.y);
                a[2] = f2bf(wa.z); a[3] = f2bf(wa.w);
                a[4] = f2bf(wb.x); a[5] = f2bf(wb.y);
                a[6] = f2bf(wb.z); a[7] = f2bf(wb.w);
                ah[mi] = a;
            }
            #pragma unroll
            for (int ni = 0; ni < 4; ++ni) {
                const int p  = ni * 16 + l15;
                const int vp = (ks >> 1) * 8 + ((((ks & 1) * 4) + quad) ^ (p & 7));
                bh[ni] = *(const shortx8*)&Xh_l[(p * 24 + vp) * 8];
            }
            #pragma unroll
            for (int mi = 0; mi < 3; ++mi)
                #pragma unroll
                for (int ni = 0; ni < 4; ++ni)
                    acc[mi][ni] = __builtin_amdgcn_mfma_f32_16x16x32_bf16(ah[mi], bh[ni], acc[mi][ni], 0, 0, 0);
        }

        __syncthreads();   // prior epilogue's T readers done before overwrite

        if (mat < 2) {
            short* T = (short*)(smem + 24576);   // 64*200*2 = 25600 B
            #pragma unroll
            for (int mi = 0; mi < 3; ++mi) {
                float4 b4 = *(const float4*)&bias[g * CG + ob + mi * 16 + quad * 4];
                const int o = ob + mi * 16 + quad * 4;
                #pragma unroll
                for (int ni = 0; ni < 4; ++ni) {
                    const int p = ni * 16 + l15;
                    T[p * 200 + o]     = f2bf(acc[mi][ni][0] + b4.x);
                    T[p * 200 + o + 1] = f2bf(acc[mi][ni][1] + b4.y);
                    T[p * 200 + o + 2] = f2bf(acc[mi][ni][2] + b4.z);
                    T[p * 200 + o + 3] = f2bf(acc[mi][ni][3] + b4.w);
                }
            }
            __syncthreads();
            #pragma unroll
            for (int hc = 0; hc < HPG; ++hc) {
                const size_t nh = (size_t)n * HH + g * HPG + hc;
                #pragma unroll
                for (int half = 0; half < 2; ++half) {
                    const int idx = tid + half * 256;
                    const int p  = idx >> 3;
                    const int dc = (idx & 7) * 8;
                    *(shortx8*)&Y[(nh * WW + p0 + p) * DD + dc] =
                        *(const shortx8*)&T[p * 200 + hc * 64 + dc];
                }
            }
        } else {
            short* T = (short*)(smem + 24576);   // 192*68*2 = 26112 B
            #pragma unroll
            for (int mi = 0; mi < 3; ++mi) {
                float4 b4 = *(const float4*)&bias[g * CG + ob + mi * 16 + quad * 4];
                const int o = ob + mi * 16 + quad * 4;
                #pragma unroll
                for (int ni = 0; ni < 4; ++ni) {
                    const int p = ni * 16 + l15;
                    T[(o)     * 68 + p] = f2bf(acc[mi][ni][0] + b4.x);
                    T[(o + 1) * 68 + p] = f2bf(acc[mi][ni][1] + b4.y);
                    T[(o + 2) * 68 + p] = f2bf(acc[mi][ni][2] + b4.z);
                    T[(o + 3) * 68 + p] = f2bf(acc[mi][ni][3] + b4.w);
                }
            }
            __syncthreads();
            #pragma unroll
            for (int pass = 0; pass < 6; ++pass) {
                const int idx = tid + pass * 256;
                const int o  = idx >> 3;
                const int pc = (idx & 7) * 8;
                const size_t nh = (size_t)n * HH + g * HPG + (o >> 6);
                const int d = o & 63;
                *(shortx8*)&Y[(nh * DD + d) * WW + p0 + pc] =
                    *(const shortx8*)&T[o * 68 + pc];
            }
        }
    }
}

// ---------------------------------------------------------------------------
// Attention (verbatim R12/R13-passing): register-resident P, pre-permuted K
// rows, conflict-free swzK/swzV, mask in LDS, ones-MFMA lsum.
// LDS 40960 B. grid: 1536 1-D blocks (XCD swizzle), block 256.
// ---------------------------------------------------------------------------
#define RST 65

__global__ __launch_bounds__(256) void attn_split(
    const short* __restrict__ Qb, const short* __restrict__ Kb,
    const short* __restrict__ Vb, const float* __restrict__ mask,
    float* __restrict__ out)
{
    __shared__ __align__(16) char smem[40960];
    // [0]:Ks0 8K [8192]:Ks1 8K [16384]:Vs0 8K [24576]:Vs1 8K [32768]: Ml 8192
    float* Ml = (float*)(smem + 32768);

    const int lin  = blockIdx.x;
    const int xcd  = lin & 7;
    const int slot = lin >> 3;               // 0..191
    const int pair = xcd * 6 + (slot >> 5);  // 0..47
    const int qt   = slot & 31;
    const int n    = pair / HH;
    const int h    = pair % HH;
    const int q0   = qt * 64;

    const int tid  = threadIdx.x;
    const int wid  = __builtin_amdgcn_readfirstlane(tid >> 6);
    const int lane = tid & 63;
    const int l15  = lane & 15;
    const int quad = lane >> 4;

    const size_t nh = (size_t)n * HH + h;
    const short* Kbase = Kb + nh * WW * DD;   // [key][d]
    const short* Vbase = Vb + nh * DD * WW;   // [d][w]

    // stage pre-transformed mask once
    {
        const float* mbase = mask + (size_t)n * WW;
        #pragma unroll
        for (int i = 0; i < WW / 256; ++i)
            Ml[tid + i * 256] = fmaf(mbase[tid + i * 256], L2E, -MSH);
    }

    shortx8 qf[2];
    {
        const short* qp = Qb + (nh * WW + q0 + wid * 16 + l15) * DD + quad * 8;
        qf[0] = *(const shortx8*)(qp);
        qf[1] = *(const shortx8*)(qp + 32);
    }

    // ones B-fragment for the row-sum MFMA (bf16 1.0 = 0x3F80)
    shortx8 onef;
    #pragma unroll
    for (int j = 0; j < 8; ++j) onef[j] = (short)0x3F80;

    floatx4 oacc[4];
    #pragma unroll
    for (int nn2 = 0; nn2 < 4; ++nn2) oacc[nn2] = (floatx4)0.0f;
    floatx4 lsum = (floatx4)0.0f;

    // hoisted staging addresses (per lane, advance per tile)
    const int r0  = wid * 16 + (lane >> 3);
    const int r1  = r0 + 8;
    const int cgk0 = (lane & 7) ^ swzK(r0);
    const int cgk1 = (lane & 7) ^ swzK(r1);
    const int cgv0 = (lane & 7) ^ swzV(r0);
    const int cgv1 = (lane & 7) ^ swzV(r1);
    const short* kp0 = Kbase + (size_t)r0 * DD + cgk0 * 8;   // += 64*DD/tile
    const short* kp1 = Kbase + (size_t)r1 * DD + cgk1 * 8;
    const short* vp0 = Vbase + (size_t)r0 * WW + cgv0 * 8;   // += 64/tile
    const short* vp1 = Vbase + (size_t)r1 * WW + cgv1 * 8;
    const int KR0 = (wid * 16) * 64, KR1 = (wid * 16 + 8) * 64;   // LDS offs

    // pre-permuted K read rows: rp(jj) = base(jj) + (l15>>2)*8 + (l15&3)
    const int rowmap = (l15 >> 2) * 8 + (l15 & 3);

    #define STAGE(j, bb)                                                      \
        do {                                                                  \
            short* ksd = (short*)(smem + (bb) * 8192);                        \
            short* vsd = (short*)(smem + 16384 + (bb) * 8192);                \
            gl_lds16(kp0 + (size_t)(j) * 64 * DD, ksd + KR0);                 \
            gl_lds16(kp1 + (size_t)(j) * 64 * DD, ksd + KR1);                 \
            gl_lds16(vp0 + (j) * 64, vsd + KR0);                              \
            gl_lds16(vp1 + (j) * 64, vsd + KR1);                              \
        } while (0)

    STAGE(0, 0);
    __syncthreads();   // tile 0 ready (also covers Ml)

    for (int kt = 0; kt < WW / 64; ++kt) {
        const int bb = kt & 1;
        if (kt + 1 < WW / 64) STAGE(kt + 1, 1 - bb);

        const short* Ks_l = (const short*)(smem + bb * 8192);
        const short* Vs_l = (const short*)(smem + 16384 + bb * 8192);
        const int k0 = kt * 64;

        shortx8 kf[4][2], vf[4][2];
        #pragma unroll
        for (int jj = 0; jj < 4; ++jj) {
            const int rp = ((jj >> 1) * 32) + ((jj & 1) * 4) + rowmap;
            #pragma unroll
            for (int hf = 0; hf < 2; ++hf)
                kf[jj][hf] = *(const shortx8*)&Ks_l[rp * 64 + (((hf * 4 + quad) ^ swzK(rp)) * 8)];
        }
        #pragma unroll
        for (int nn2 = 0; nn2 < 4; ++nn2) {
            const int r = 16 * nn2 + l15;
            #pragma unroll
            for (int hf = 0; hf < 2; ++hf)
                vf[nn2][hf] = *(const shortx8*)&Vs_l[r * 64 + (((hf * 4 + quad) ^ swzV(r)) * 8)];
        }

        // mask values follow the key permutation: phys key(jj,quad,r) =
        // base(jj) + quad*8 + r  (contiguous aligned 16B per jj)
        floatx4 mv4[4];
        #pragma unroll
        for (int jj = 0; jj < 4; ++jj) {
            const int kb = ((jj >> 1) * 32) + ((jj & 1) * 4) + quad * 8;
            mv4[jj] = *(const floatx4*)&Ml[k0 + kb];
        }

        // swapped QK^T: sacc[jj][r] = S[phys key base(jj)+quad*8+r][q=l15]
        floatx4 sacc[4];
        #pragma unroll
        for (int jj = 0; jj < 4; ++jj) {
            sacc[jj] = (floatx4)0.0f;
            sacc[jj] = __builtin_amdgcn_mfma_f32_16x16x32_bf16(kf[jj][0], qf[0], sacc[jj], 0, 0, 0);
            sacc[jj] = __builtin_amdgcn_mfma_f32_16x16x32_bf16(kf[jj][1], qf[1], sacc[jj], 0, 0, 0);
        }

        // exp + pack straight into PV A-fragment order (no cross-lane)
        int s[4][2];
        #pragma unroll
        for (int jj = 0; jj < 4; ++jj) {
            float p0 = fast_exp2(fmaf(sacc[jj][0], C18, mv4[jj][0]));
            float p1 = fast_exp2(fmaf(sacc[jj][1], C18, mv4[jj][1]));
            float p2 = fast_exp2(fmaf(sacc[jj][2], C18, mv4[jj][2]));
            float p3 = fast_exp2(fmaf(sacc[jj][3], C18, mv4[jj][3]));
            s[jj][0] = cvtpk(p0, p1);
            s[jj][1] = cvtpk(p2, p3);
        }
        shortx8 pf0 = mk8(s[0][0], s[0][1], s[1][0], s[1][1]);   // keys 0..31
        shortx8 pf1 = mk8(s[2][0], s[2][1], s[3][0], s[3][1]);   // keys 32..63

        #pragma unroll
        for (int nn2 = 0; nn2 < 4; ++nn2) {
            oacc[nn2] = __builtin_amdgcn_mfma_f32_16x16x32_bf16(pf0, vf[nn2][0], oacc[nn2], 0, 0, 0);
            oacc[nn2] = __builtin_amdgcn_mfma_f32_16x16x32_bf16(pf1, vf[nn2][1], oacc[nn2], 0, 0, 0);
        }
        // softmax denominator: rowsum(P), same q=quad*4+r layout as oacc
        lsum = __builtin_amdgcn_mfma_f32_16x16x32_bf16(pf0, onef, lsum, 0, 0, 0);
        lsum = __builtin_amdgcn_mfma_f32_16x16x32_bf16(pf1, onef, lsum, 0, 0, 0);

        __syncthreads();   // drains next-tile loads + protects bb for reuse
    }
    #undef STAGE

    float linv[4];
    #pragma unroll
    for (int r = 0; r < 4; ++r) linv[r] = 1.0f / lsum[r];

    float* Ol = (float*)smem;
    #pragma unroll
    for (int nn2 = 0; nn2 < 4; ++nn2)
        #pragma unroll
        for (int r = 0; r < 4; ++r)
            Ol[(wid * 16 + quad * 4 + r) * RST + nn2 * 16 + l15] = oacc[nn2][r] * linv[r];
    __syncthreads();

    float* obase = out + (nh * DD) * WW + q0;
    #pragma unroll
    for (int it = 0; it < 4; ++it) {
        const int idx = tid + it * 256;
        const int q4 = (idx & 15) * 4;
        const int d  = idx >> 4;
        floatx4 v;
        #pragma unroll
        for (int i = 0; i < 4; ++i) v[i] = Ol[(q4 + i) * RST + d];
        *(floatx4*)&obase[(size_t)d * WW + q4] = v;
    }
}

// ---------------------------------------------------------------------------
extern "C" void kernel_launch(void* const* d_in, const int* in_sizes, int n_in,
                              void* d_out, int out_size, void* d_ws, size_t ws_size,
                              hipStream_t stream) {
    const float* x    = (const float*)d_in[0];
    const float* mask = (const float*)d_in[1];
    const float* wq   = (const float*)d_in[2];
    const float* bq   = (const float*)d_in[3];
    const float* wk   = (const float*)d_in[4];
    const float* bk   = (const float*)d_in[5];
    const float* wv   = (const float*)d_in[6];
    const float* bv   = (const float*)d_in[7];
    float* out = (float*)d_out;

    const size_t per = (size_t)NB * HH * WW * DD;   // 6,291,456
    short* Qb  = (short*)d_ws;
    short* Kb  = Qb + per;
    short* Vb  = Kb + per;

    hipLaunchKernelGGL(qkv_gemm, dim3(512), dim3(256), 0, stream,
                       x, wq, wk, wv, bq, bk, bv, Qb, Kb, Vb);
    hipLaunchKernelGGL(attn_split, dim3(1536), dim3(256), 0, stream,
                       Qb, Kb, Vb, mask, out);
}

// Round 15
// 170.776 us; speedup vs baseline: 1.1174x; 1.1174x over previous
//
#include <hip/hip_runtime.h>
#include <math.h>

typedef __attribute__((ext_vector_type(4))) float floatx4;
typedef __attribute__((ext_vector_type(8))) short shortx8;   // 8 bf16
typedef __attribute__((ext_vector_type(4))) short shortx4;   // 4 bf16 (8B)

#define NB 4
#define CC 768
#define WW 2048
#define HH 12
#define DD 64
#define GG 4
#define CG 192
#define HPG 3
#define L2E 1.4426950408889634f
#define C18 0.18033688011112043f   // 0.125 * log2(e)
#define MSH 11.541560327111707f    // 8.0 * log2(e)  (fixed softmax shift)
#define WSZ (GG * CG * CG)         // 147456

__device__ __forceinline__ float fast_exp2(float x) {
    return __builtin_amdgcn_exp2f(x);   // v_exp_f32 (log2 domain)
}

__device__ __forceinline__ short f2bf(float f) {
    union { float f; unsigned u; } v; v.f = f;
    unsigned r = v.u + 0x7fffu + ((v.u >> 16) & 1u);   // RNE
    return (short)(r >> 16);
}

// v_cvt_pk_bf16_f32: lo16 <- src0, hi16 <- src1 (RNE)  [learn_hip m214v22]
__device__ __forceinline__ int cvtpk(float lo, float hi) {
    int r;
    asm("v_cvt_pk_bf16_f32 %0, %1, %2" : "=v"(r) : "v"(lo), "v"(hi));
    return r;
}

__device__ __forceinline__ shortx8 mk8(int a, int b, int c, int d) {
    union { int i[4]; shortx8 h; } u;
    u.i[0] = a; u.i[1] = b; u.i[2] = c; u.i[3] = d;
    return u.h;
}

// K-buffer swizzle (R12-verified: conflicts 6.68M -> 0.39M). K-read 8-lane
// service groups cover rows {B..B+3, B+8..B+11}; fK(r) = (r1 r0, r3<<2) is
// bank-distinct on every group. Semantics swizzle-independent (pre-swizzled
// global source; read XORs the same fK(r) back out).
__device__ __forceinline__ int swzK(int r) {
    return (r & 3) | (((r >> 3) & 1) << 2);
}
// V-buffer swizzle: V read groups cover 8 CONSECUTIVE rows c..c+7 ->
// identity low-3-bits is bijective per service group (R4-verified).
__device__ __forceinline__ int swzV(int r) {
    return r & 7;
}

// async global->LDS, 16B per lane; lds base must be wave-uniform
__device__ __forceinline__ void gl_lds16(const void* g, void* l) {
    __builtin_amdgcn_global_load_lds(
        (const __attribute__((address_space(1))) unsigned int*)g,
        (__attribute__((address_space(3))) unsigned int*)l, 16, 0, 0);
}

// ---------------------------------------------------------------------------
// prep_w: weights -> Wf fragment-major. grid: 576 blocks (WSZ/256).
// (R14 lesson: do NOT fold this into qkv — per-block re-conversion of the
// group's 147KB weights cost +15us; one-shot precompute amortizes it.)
// ---------------------------------------------------------------------------
__global__ __launch_bounds__(256) void prep_w(
    const float* __restrict__ wq, const float* __restrict__ wk,
    const float* __restrict__ wv, short* __restrict__ Wf)
{
    const int t = blockIdx.x * 256 + threadIdx.x;  // < WSZ
    const int g  = t / (CG * CG);
    const int r  = t - g * (CG * CG);
    const int o  = r / CG;
    const int k  = r - o * CG;
    const int off = (((g * 12 + (o >> 4)) * 6 + (k >> 5)) * 512)
                  + ((k >> 3) & 3) * 128 + (o & 15) * 8 + (k & 7);
    const float* src[3] = {wq, wk, wv};
    #pragma unroll
    for (int m = 0; m < 3; ++m)
        Wf[m * WSZ + off] = f2bf(src[m][t]);
}

// ---------------------------------------------------------------------------
// qkv_gemm v3: ONE block per tile computes ALL THREE mats (Q,K,V).
// x tile staged+transposed ONCE; MFMA loop + epilogue wrapped in a mat loop.
// [0,24576): Xh_l  [24576,50688): scratch (Th staging, then T epilogue).
// grid: 512 1-D blocks (2/CU, 1 pass).
// ---------------------------------------------------------------------------
__global__ __launch_bounds__(256) void qkv_gemm(
    const float* __restrict__ x, const short* __restrict__ Wf,
    const float* __restrict__ bq, const float* __restrict__ bk,
    const float* __restrict__ bv,
    short* __restrict__ Qb, short* __restrict__ Kb, short* __restrict__ Vb)
{
    __shared__ __align__(16) char smem[50688];
    short* Xh_l = (short*)smem;              // 24576 B, [p][24 chunks] swz
    short* Th   = (short*)(smem + 24576);    // staging transpose scratch

    const int tile = blockIdx.x;            // 0..511
    const int p0   = (tile & 31) * 64;
    const int g    = (tile >> 5) & 3;
    const int n    = tile >> 7;

    const int tid  = threadIdx.x;
    const int wid  = __builtin_amdgcn_readfirstlane(tid >> 6);
    const int lane = tid & 63;
    const int l15  = lane & 15;
    const int quad = lane >> 4;
    const int ob   = wid * 48;

    // ---- fused transpose staging (ONCE): x [c][w] f32 -> Xh_l swizzled ----
    {
        const int w  = tid & 63;
        const int cb = (tid >> 6) * 16;
        const int wr = tid >> 2;
        const int cc = (tid & 3) * 16;       // shorts within slab
        for (int s = 0; s < 3; ++s) {
            const float* xb = x + ((size_t)n * CC + g * CG + s * 64 + cb) * WW + p0 + w;
            float xv[16];
            #pragma unroll
            for (int j = 0; j < 16; ++j) xv[j] = xb[(size_t)j * WW];
            shortx8 h0, h1;
            #pragma unroll
            for (int j = 0; j < 8; ++j) { h0[j] = f2bf(xv[j]); h1[j] = f2bf(xv[j + 8]); }
            *(shortx8*)&Th[w * 72 + cb]     = h0;
            *(shortx8*)&Th[w * 72 + cb + 8] = h1;
            __syncthreads();
            shortx8 v0 = *(const shortx8*)&Th[wr * 72 + cc];
            shortx8 v1 = *(const shortx8*)&Th[wr * 72 + cc + 8];
            const int ch0 = s * 8 + (cc >> 3);           // even chunk
            const int ch1 = ch0 + 1;
            const int sc0 = (ch0 & ~7) | ((ch0 & 7) ^ (wr & 7));
            const int sc1 = (ch1 & ~7) | ((ch1 & 7) ^ (wr & 7));
            *(shortx8*)&Xh_l[(wr * 24 + sc0) * 8] = v0;
            *(shortx8*)&Xh_l[(wr * 24 + sc1) * 8] = v1;
            __syncthreads();                 // Th reuse / final: frags ready
        }
    }

    #pragma unroll 1
    for (int mat = 0; mat < 3; ++mat) {
        floatx4 acc[3][4];
        #pragma unroll
        for (int mi = 0; mi < 3; ++mi)
            #pragma unroll
            for (int ni = 0; ni < 4; ++ni) acc[mi][ni] = (floatx4)0.0f;

        const short* wfm = Wf + (size_t)mat * WSZ + lane * 8;

        #pragma unroll
        for (int ks = 0; ks < 6; ++ks) {
            shortx8 ah[3], bh[4];
            #pragma unroll
            for (int mi = 0; mi < 3; ++mi)
                ah[mi] = *(const shortx8*)(wfm + (((g * 12 + wid * 3 + mi) * 6 + ks) << 9));
            #pragma unroll
            for (int ni = 0; ni < 4; ++ni) {
                const int p  = ni * 16 + l15;
                const int vp = (ks >> 1) * 8 + ((((ks & 1) * 4) + quad) ^ (p & 7));
                bh[ni] = *(const shortx8*)&Xh_l[(p * 24 + vp) * 8];
            }
            #pragma unroll
            for (int mi = 0; mi < 3; ++mi)
                #pragma unroll
                for (int ni = 0; ni < 4; ++ni)
                    acc[mi][ni] = __builtin_amdgcn_mfma_f32_16x16x32_bf16(ah[mi], bh[ni], acc[mi][ni], 0, 0, 0);
        }

        const float* bias = (mat == 0) ? bq : (mat == 1) ? bk : bv;
        short* Y = (mat == 0) ? Qb : (mat == 1) ? Kb : Vb;

        __syncthreads();   // prior epilogue's T readers done before overwrite

        if (mat < 2) {
            short* T = (short*)(smem + 24576);   // 64*200*2 = 25600 B
            #pragma unroll
            for (int mi = 0; mi < 3; ++mi) {
                float4 b4 = *(const float4*)&bias[g * CG + ob + mi * 16 + quad * 4];
                const int o = ob + mi * 16 + quad * 4;
                #pragma unroll
                for (int ni = 0; ni < 4; ++ni) {
                    const int p = ni * 16 + l15;
                    T[p * 200 + o]     = f2bf(acc[mi][ni][0] + b4.x);
                    T[p * 200 + o + 1] = f2bf(acc[mi][ni][1] + b4.y);
                    T[p * 200 + o + 2] = f2bf(acc[mi][ni][2] + b4.z);
                    T[p * 200 + o + 3] = f2bf(acc[mi][ni][3] + b4.w);
                }
            }
            __syncthreads();
            #pragma unroll
            for (int hc = 0; hc < HPG; ++hc) {
                const size_t nh = (size_t)n * HH + g * HPG + hc;
                #pragma unroll
                for (int half = 0; half < 2; ++half) {
                    const int idx = tid + half * 256;
                    const int p  = idx >> 3;
                    const int dc = (idx & 7) * 8;
                    *(shortx8*)&Y[(nh * WW + p0 + p) * DD + dc] =
                        *(const shortx8*)&T[p * 200 + hc * 64 + dc];
                }
            }
        } else {
            short* T = (short*)(smem + 24576);   // 192*68*2 = 26112 B
            #pragma unroll
            for (int mi = 0; mi < 3; ++mi) {
                float4 b4 = *(const float4*)&bias[g * CG + ob + mi * 16 + quad * 4];
                const int o = ob + mi * 16 + quad * 4;
                #pragma unroll
                for (int ni = 0; ni < 4; ++ni) {
                    const int p = ni * 16 + l15;
                    T[(o)     * 68 + p] = f2bf(acc[mi][ni][0] + b4.x);
                    T[(o + 1) * 68 + p] = f2bf(acc[mi][ni][1] + b4.y);
                    T[(o + 2) * 68 + p] = f2bf(acc[mi][ni][2] + b4.z);
                    T[(o + 3) * 68 + p] = f2bf(acc[mi][ni][3] + b4.w);
                }
            }
            __syncthreads();
            #pragma unroll
            for (int pass = 0; pass < 6; ++pass) {
                const int idx = tid + pass * 256;
                const int o  = idx >> 3;
                const int pc = (idx & 7) * 8;
                const size_t nh = (size_t)n * HH + g * HPG + (o >> 6);
                const int d = o & 63;
                *(shortx8*)&Y[(nh * DD + d) * WW + p0 + pc] =
                    *(const shortx8*)&T[o * 68 + pc];
            }
        }
    }
}

// ---------------------------------------------------------------------------
// Attention (verbatim R12/R13-passing): register-resident P, pre-permuted K
// rows, conflict-free swzK/swzV, mask in LDS, ones-MFMA lsum.
// LDS 40960 B. grid: 1536 1-D blocks (XCD swizzle), block 256.
// ---------------------------------------------------------------------------
#define RST 65

__global__ __launch_bounds__(256) void attn_split(
    const short* __restrict__ Qb, const short* __restrict__ Kb,
    const short* __restrict__ Vb, const float* __restrict__ mask,
    float* __restrict__ out)
{
    __shared__ __align__(16) char smem[40960];
    // [0]:Ks0 8K [8192]:Ks1 8K [16384]:Vs0 8K [24576]:Vs1 8K [32768]: Ml 8192
    float* Ml = (float*)(smem + 32768);

    const int lin  = blockIdx.x;
    const int xcd  = lin & 7;
    const int slot = lin >> 3;               // 0..191
    const int pair = xcd * 6 + (slot >> 5);  // 0..47
    const int qt   = slot & 31;
    const int n    = pair / HH;
    const int h    = pair % HH;
    const int q0   = qt * 64;

    const int tid  = threadIdx.x;
    const int wid  = __builtin_amdgcn_readfirstlane(tid >> 6);
    const int lane = tid & 63;
    const int l15  = lane & 15;
    const int quad = lane >> 4;

    const size_t nh = (size_t)n * HH + h;
    const short* Kbase = Kb + nh * WW * DD;   // [key][d]
    const short* Vbase = Vb + nh * DD * WW;   // [d][w]

    // stage pre-transformed mask once
    {
        const float* mbase = mask + (size_t)n * WW;
        #pragma unroll
        for (int i = 0; i < WW / 256; ++i)
            Ml[tid + i * 256] = fmaf(mbase[tid + i * 256], L2E, -MSH);
    }

    shortx8 qf[2];
    {
        const short* qp = Qb + (nh * WW + q0 + wid * 16 + l15) * DD + quad * 8;
        qf[0] = *(const shortx8*)(qp);
        qf[1] = *(const shortx8*)(qp + 32);
    }

    // ones B-fragment for the row-sum MFMA (bf16 1.0 = 0x3F80)
    shortx8 onef;
    #pragma unroll
    for (int j = 0; j < 8; ++j) onef[j] = (short)0x3F80;

    floatx4 oacc[4];
    #pragma unroll
    for (int nn2 = 0; nn2 < 4; ++nn2) oacc[nn2] = (floatx4)0.0f;
    floatx4 lsum = (floatx4)0.0f;

    // hoisted staging addresses (per lane, advance per tile)
    const int r0  = wid * 16 + (lane >> 3);
    const int r1  = r0 + 8;
    const int cgk0 = (lane & 7) ^ swzK(r0);
    const int cgk1 = (lane & 7) ^ swzK(r1);
    const int cgv0 = (lane & 7) ^ swzV(r0);
    const int cgv1 = (lane & 7) ^ swzV(r1);
    const short* kp0 = Kbase + (size_t)r0 * DD + cgk0 * 8;   // += 64*DD/tile
    const short* kp1 = Kbase + (size_t)r1 * DD + cgk1 * 8;
    const short* vp0 = Vbase + (size_t)r0 * WW + cgv0 * 8;   // += 64/tile
    const short* vp1 = Vbase + (size_t)r1 * WW + cgv1 * 8;
    const int KR0 = (wid * 16) * 64, KR1 = (wid * 16 + 8) * 64;   // LDS offs

    // pre-permuted K read rows: rp(jj) = base(jj) + (l15>>2)*8 + (l15&3)
    const int rowmap = (l15 >> 2) * 8 + (l15 & 3);

    #define STAGE(j, bb)                                                      \
        do {                                                                  \
            short* ksd = (short*)(smem + (bb) * 8192);                        \
            short* vsd = (short*)(smem + 16384 + (bb) * 8192);                \
            gl_lds16(kp0 + (size_t)(j) * 64 * DD, ksd + KR0);                 \
            gl_lds16(kp1 + (size_t)(j) * 64 * DD, ksd + KR1);                 \
            gl_lds16(vp0 + (j) * 64, vsd + KR0);                              \
            gl_lds16(vp1 + (j) * 64, vsd + KR1);                              \
        } while (0)

    STAGE(0, 0);
    __syncthreads();   // tile 0 ready (also covers Ml)

    for (int kt = 0; kt < WW / 64; ++kt) {
        const int bb = kt & 1;
        if (kt + 1 < WW / 64) STAGE(kt + 1, 1 - bb);

        const short* Ks_l = (const short*)(smem + bb * 8192);
        const short* Vs_l = (const short*)(smem + 16384 + bb * 8192);
        const int k0 = kt * 64;

        shortx8 kf[4][2], vf[4][2];
        #pragma unroll
        for (int jj = 0; jj < 4; ++jj) {
            const int rp = ((jj >> 1) * 32) + ((jj & 1) * 4) + rowmap;
            #pragma unroll
            for (int hf = 0; hf < 2; ++hf)
                kf[jj][hf] = *(const shortx8*)&Ks_l[rp * 64 + (((hf * 4 + quad) ^ swzK(rp)) * 8)];
        }
        #pragma unroll
        for (int nn2 = 0; nn2 < 4; ++nn2) {
            const int r = 16 * nn2 + l15;
            #pragma unroll
            for (int hf = 0; hf < 2; ++hf)
                vf[nn2][hf] = *(const shortx8*)&Vs_l[r * 64 + (((hf * 4 + quad) ^ swzV(r)) * 8)];
        }

        // mask values follow the key permutation: phys key(jj,quad,r) =
        // base(jj) + quad*8 + r  (contiguous aligned 16B per jj)
        floatx4 mv4[4];
        #pragma unroll
        for (int jj = 0; jj < 4; ++jj) {
            const int kb = ((jj >> 1) * 32) + ((jj & 1) * 4) + quad * 8;
            mv4[jj] = *(const floatx4*)&Ml[k0 + kb];
        }

        // swapped QK^T: sacc[jj][r] = S[phys key base(jj)+quad*8+r][q=l15]
        floatx4 sacc[4];
        #pragma unroll
        for (int jj = 0; jj < 4; ++jj) {
            sacc[jj] = (floatx4)0.0f;
            sacc[jj] = __builtin_amdgcn_mfma_f32_16x16x32_bf16(kf[jj][0], qf[0], sacc[jj], 0, 0, 0);
            sacc[jj] = __builtin_amdgcn_mfma_f32_16x16x32_bf16(kf[jj][1], qf[1], sacc[jj], 0, 0, 0);
        }

        // exp + pack straight into PV A-fragment order (no cross-lane)
        int s[4][2];
        #pragma unroll
        for (int jj = 0; jj < 4; ++jj) {
            float p0 = fast_exp2(fmaf(sacc[jj][0], C18, mv4[jj][0]));
            float p1 = fast_exp2(fmaf(sacc[jj][1], C18, mv4[jj][1]));
            float p2 = fast_exp2(fmaf(sacc[jj][2], C18, mv4[jj][2]));
            float p3 = fast_exp2(fmaf(sacc[jj][3], C18, mv4[jj][3]));
            s[jj][0] = cvtpk(p0, p1);
            s[jj][1] = cvtpk(p2, p3);
        }
        shortx8 pf0 = mk8(s[0][0], s[0][1], s[1][0], s[1][1]);   // keys 0..31
        shortx8 pf1 = mk8(s[2][0], s[2][1], s[3][0], s[3][1]);   // keys 32..63

        #pragma unroll
        for (int nn2 = 0; nn2 < 4; ++nn2) {
            oacc[nn2] = __builtin_amdgcn_mfma_f32_16x16x32_bf16(pf0, vf[nn2][0], oacc[nn2], 0, 0, 0);
            oacc[nn2] = __builtin_amdgcn_mfma_f32_16x16x32_bf16(pf1, vf[nn2][1], oacc[nn2], 0, 0, 0);
        }
        // softmax denominator: rowsum(P), same q=quad*4+r layout as oacc
        lsum = __builtin_amdgcn_mfma_f32_16x16x32_bf16(pf0, onef, lsum, 0, 0, 0);
        lsum = __builtin_amdgcn_mfma_f32_16x16x32_bf16(pf1, onef, lsum, 0, 0, 0);

        __syncthreads();   // drains next-tile loads + protects bb for reuse
    }
    #undef STAGE

    float linv[4];
    #pragma unroll
    for (int r = 0; r < 4; ++r) linv[r] = 1.0f / lsum[r];

    float* Ol = (float*)smem;
    #pragma unroll
    for (int nn2 = 0; nn2 < 4; ++nn2)
        #pragma unroll
        for (int r = 0; r < 4; ++r)
            Ol[(wid * 16 + quad * 4 + r) * RST + nn2 * 16 + l15] = oacc[nn2][r] * linv[r];
    __syncthreads();

    float* obase = out + (nh * DD) * WW + q0;
    #pragma unroll
    for (int it = 0; it < 4; ++it) {
        const int idx = tid + it * 256;
        const int q4 = (idx & 15) * 4;
        const int d  = idx >> 4;
        floatx4 v;
        #pragma unroll
        for (int i = 0; i < 4; ++i) v[i] = Ol[(q4 + i) * RST + d];
        *(floatx4*)&obase[(size_t)d * WW + q4] = v;
    }
}

// ---------------------------------------------------------------------------
extern "C" void kernel_launch(void* const* d_in, const int* in_sizes, int n_in,
                              void* d_out, int out_size, void* d_ws, size_t ws_size,
                              hipStream_t stream) {
    const float* x    = (const float*)d_in[0];
    const float* mask = (const float*)d_in[1];
    const float* wq   = (const float*)d_in[2];
    const float* bq   = (const float*)d_in[3];
    const float* wk   = (const float*)d_in[4];
    const float* bk   = (const float*)d_in[5];
    const float* wv   = (const float*)d_in[6];
    const float* bv   = (const float*)d_in[7];
    float* out = (float*)d_out;

    const size_t per = (size_t)NB * HH * WW * DD;   // 6,291,456
    short* Qb  = (short*)d_ws;
    short* Kb  = Qb + per;
    short* Vb  = Kb + per;
    short* Wfp = Vb + per;                           // 3*WSZ shorts

    hipLaunchKernelGGL(prep_w, dim3(WSZ / 256), dim3(256), 0, stream,
                       wq, wk, wv, Wfp);
    hipLaunchKernelGGL(qkv_gemm, dim3(512), dim3(256), 0, stream,
                       x, Wfp, bq, bk, bv, Qb, Kb, Vb);
    hipLaunchKernelGGL(attn_split, dim3(1536), dim3(256), 0, stream,
                       Qb, Kb, Vb, mask, out);
}